// Round 3
// baseline (318.053 us; speedup 1.0000x reference)
//
#include <hip/hip_runtime.h>
#include <hip/hip_bf16.h>
#include <math.h>

#define B_ 16
#define T_ 512
#define H_ 768
#define S_ 32
#define L_ 50
#define NT_ 3
#define HS_ 3072
#define CH_ 32
#define CT_ 16  // T_/CH_

// Row compaction: starts in [1,400), L=50  =>  pc <= 448, pre-index <= 449.
// TX_=464 rows/batch (29*16 chunks) cover all live rows; 256-aligned regions
// so every 256-row GEMM m-tile uses a single W-panel.
#define TX_ 464
// A-buffer row layout (bf16, 768 cols), compacted:
//   [0, 7424)        hb   = bf16(h[b,t]), row b*464+t, t<464          (29 tiles)
//   [7424, 14848)    preb = bf16(cumsum), row 7424 + b*464 + u        (29 tiles)
//   [14848, 15360)   Gb   = gathered span-start rows (512)            (2 tiles)
//   [15360, 15376)   cls rows (16); rows 15376..15615 pad (discarded) (1 tile)
#define YB2 7424
#define GB 14848
#define CLSB 15360
#define XYROWS 14848
#define AROWS 15616        // = 61 * 256 exactly
#define NKT 24             // 768 / BK32
#define SLOT_SH 16384      // shorts per LDS slot: A 8192 + B 8192 (32 KiB)

typedef __attribute__((ext_vector_type(8))) short short8;
typedef __attribute__((ext_vector_type(4))) float f32x4;

__device__ __forceinline__ unsigned short f2bf(float f) {
    __hip_bfloat16 b = __float2bfloat16(f);
    return *(unsigned short*)&b;
}
__device__ __forceinline__ float bf2f(unsigned short u) {
    union { unsigned int i; float f; } v; v.i = ((unsigned int)u) << 16; return v.f;
}
__device__ __forceinline__ void load_lds16(const void* g, void* l) {
    __builtin_amdgcn_global_load_lds((__attribute__((address_space(1))) void*)g,
                                     (__attribute__((address_space(3))) void*)l, 16, 0, 0);
}
__device__ __forceinline__ ushort4 pack4(float4 v) {
    ushort4 o; o.x = f2bf(v.x); o.y = f2bf(v.y); o.z = f2bf(v.z); o.w = f2bf(v.w);
    return o;
}

// branch-free exact-gelu: Abramowitz-Stegun 3-term erf, max err 2.5e-5
__device__ __forceinline__ float gelu_exact(float v) {
    float a = fabsf(v) * 0.70710678118654752f;
    float t = __builtin_amdgcn_rcpf(fmaf(a, 0.47047f, 1.0f));
    float poly = t * fmaf(t, fmaf(t, 0.7478556f, -0.0958798f), 0.3480242f);
    float e = __builtin_amdgcn_exp2f(a * a * -1.4426950408889634f);
    float erfa = fmaf(-poly, e, 1.0f);
    float erfv = copysignf(erfa, v);
    return 0.5f * v * (1.0f + erfv);
}

// ---------------------------------------------------------------------------
// cumsum pass1: per-(b,chunk) partial sums, float4-vectorized over hd
// ---------------------------------------------------------------------------
__global__ __launch_bounds__(256) void cumsum_pass1(const float4* __restrict__ h4,
                                                    float4* __restrict__ partial) {
    int idx = blockIdx.x * 256 + threadIdx.x;        // (b, ch, hd4)
    int hd4 = idx % 192; int t = idx / 192; int ch = t % CH_; int b = t / CH_;
    const float4* hp = h4 + ((size_t)b * T_ + ch * CT_) * 192 + hd4;
    float4 acc = {0.f, 0.f, 0.f, 0.f};
#pragma unroll
    for (int tt = 0; tt < CT_; tt++) {
        float4 v = hp[(size_t)tt * 192];
        acc.x += v.x; acc.y += v.y; acc.z += v.z; acc.w += v.w;
    }
    partial[idx] = acc;
}

// pass3 (chunk prefix folded in): emit bf16 h + bf16 cumsum into compacted A.
// Dead chunks early-out.
__global__ __launch_bounds__(256) void cumsum_pass3(const float4* __restrict__ h4,
                                                    const float4* __restrict__ partial,
                                                    ushort4* __restrict__ Ab4) {
    int idx = blockIdx.x * 256 + threadIdx.x;        // (b, ch, hd4)
    int hd4 = idx % 192; int t = idx / 192; int ch = t % CH_; int b = t / CH_;
    if (ch * CT_ >= TX_) return;                     // dead chunk
    float4 acc = {0.f, 0.f, 0.f, 0.f};
#pragma unroll
    for (int c = 0; c < CH_; c++) {
        if (c < ch) {
            float4 v = partial[((size_t)b * CH_ + c) * 192 + hd4];
            acc.x += v.x; acc.y += v.y; acc.z += v.z; acc.w += v.w;
        }
    }
    const float4* hp = h4 + ((size_t)b * T_ + ch * CT_) * 192 + hd4;
    if (ch == 0) {
        ushort4 z = {0, 0, 0, 0};
        Ab4[((size_t)(YB2 + b * TX_)) * 192 + hd4] = z;   // pre[b][0] = 0
    }
#pragma unroll
    for (int tt = 0; tt < CT_; tt++) {
        int t2 = ch * CT_ + tt;
        float4 hv = hp[(size_t)tt * 192];
        if (t2 < TX_)
            Ab4[((size_t)(b * TX_ + t2)) * 192 + hd4] = pack4(hv);
        acc.x += hv.x; acc.y += hv.y; acc.z += hv.z; acc.w += hv.w;
        if (t2 + 1 < TX_)
            Ab4[((size_t)(YB2 + b * TX_ + t2 + 1)) * 192 + hd4] = pack4(acc);
    }
}

// ---------------------------------------------------------------------------
// gather span-start rows (512) + cls rows (16) into A
// ---------------------------------------------------------------------------
__global__ void gather_kernel(const float* __restrict__ h,
                              const int* __restrict__ starts,
                              __hip_bfloat16* __restrict__ Ab) {
    int r = blockIdx.x;
    int src_row, dst_row;
    if (r < B_ * S_) {
        int b = r / S_;
        int sv = starts[r];
        int sc = min(max(sv, 0), T_ - 1);
        src_row = b * T_ + sc;
        dst_row = GB + r;
    } else {
        int b = r - B_ * S_;
        src_row = b * T_;
        dst_row = CLSB + b;
    }
    __hip_bfloat16* dst = Ab + (size_t)dst_row * H_;
    const float* src = h + (size_t)src_row * H_;
    for (int j = threadIdx.x; j < H_; j += 256)
        dst[j] = __float2bfloat16(src[j]);
}

// ---------------------------------------------------------------------------
// W1 (3072x3072 fp32) -> 4 transposed bf16 panels Wt[p][n=3072][k=768]
// ---------------------------------------------------------------------------
__global__ __launch_bounds__(256) void transpose_w(const float* __restrict__ W1,
                                                   __hip_bfloat16* __restrict__ Wt) {
    __shared__ float tile[64][65];
    int n0 = blockIdx.x * 64, k0 = blockIdx.y * 64;
    int c = threadIdx.x & 63, r0 = threadIdx.x >> 6;
#pragma unroll
    for (int i = 0; i < 16; i++) {
        int r = r0 + i * 4;
        tile[r][c] = W1[(size_t)(k0 + r) * HS_ + n0 + c];
    }
    __syncthreads();
    int p = k0 / H_, kl = k0 % H_;
    __hip_bfloat16* out = Wt + (size_t)p * HS_ * H_;
#pragma unroll
    for (int i = 0; i < 16; i++) {
        int r = r0 + i * 4;
        out[(size_t)(n0 + r) * H_ + kl + c] = __float2bfloat16(tile[c][r]);
    }
}

// ---------------------------------------------------------------------------
// mega MFMA GEMM over 15616 compacted A rows (X | Y | ST | CC+pad).
// 256x256 tile, 8 waves (2M x 4N), 16x16x32 bf16, BK=32.
// LDS: ring of 4 slots, slot = one K-tile (A 16K | B 16K = 32 KiB).
// XOR swizzle: 16B chunk p of row r holds logical chunk p ^ ((r>>1)&3)
//   (PMC-verified conflict-free in r2). global_load_lds dest is linear, so
//   the swizzle is applied by permuting the per-lane GLOBAL source k-offset.
// m201-faithful phase order (the r2 deviation was: lgkm0 BEFORE the barrier,
// exposing full LDS latency per phase; m201 puts the barrier between
// read-issue and lgkm-wait so latency drains during barrier-wait):
//   P0: reads a0,b (8); stage A(kt+3);                barrier; lgkm0; 16 MFMA; barrier
//   P1: reads a1 (4);   stage B(kt+3); vmcnt(8);      barrier; lgkm0; 16 MFMA; barrier
// vmcnt(8) = next slot staged (4 loads/wave/tile, 3 tiles ahead); drains
// 8->4->0 in the last 3 tiles only. 4 barriers/BK=32 = m201's rate.
// grid: 732 blocks, bijective XCD swizzle (m-chunks per XCD -> A L2-resident).
// ---------------------------------------------------------------------------
__device__ __forceinline__ void mfma16(const short8 (&a)[4], const short8 (&b)[4],
                                       f32x4 (&acc)[8][4], int off) {
#pragma unroll
    for (int mf = 0; mf < 4; ++mf)
#pragma unroll
        for (int nf = 0; nf < 4; ++nf)
            acc[off + mf][nf] = __builtin_amdgcn_mfma_f32_16x16x32_bf16(
                a[mf], b[nf], acc[off + mf][nf], 0, 0, 0);
}

#define STAGE_A(nslot, k0_) {                                                  \
    char* d_ = (char*)(nslot) + dstoff;                                        \
    load_lds16(pA + (k0_), d_);                                                \
    load_lds16(pA + (size_t)128 * H_ + (k0_), d_ + 8192);                      \
}
#define STAGE_B(nslot, k0_) {                                                  \
    char* d_ = (char*)(nslot) + 16384 + dstoff;                                \
    load_lds16(pB + (k0_), d_);                                                \
    load_lds16(pB + (size_t)128 * H_ + (k0_), d_ + 8192);                      \
}

#define TILE_STEP(kt, WAITSTR, DO_STAGE)                                       \
  {                                                                            \
    const short* slot = lds + ((kt) & 3) * SLOT_SH;                            \
    short* nslot = lds + (((kt) + 3) & 3) * SLOT_SH;                           \
    short8 a[4], b[4];                                                         \
    /* P0: issue reads, issue A-stage, THEN barrier (read latency drains    */ \
    /* while waiting), THEN lgkm0 (cheap), THEN MFMA cluster.               */ \
    _Pragma("unroll")                                                          \
    for (int i = 0; i < 4; ++i)                                                \
      a[i] = *(const short8*)&slot[(wr * 128 + i * 16 + l15) * 32 + pcs];      \
    _Pragma("unroll")                                                          \
    for (int i = 0; i < 4; ++i)                                                \
      b[i] = *(const short8*)&slot[8192 + (wc * 64 + i * 16 + l15) * 32 + pcs];\
    if (DO_STAGE) { STAGE_A(nslot, ((kt) + 3) * 32) }                          \
    __builtin_amdgcn_s_barrier();                                              \
    asm volatile("s_waitcnt lgkmcnt(0)" ::: "memory");                         \
    __builtin_amdgcn_sched_barrier(0);                                         \
    __builtin_amdgcn_s_setprio(1);                                             \
    mfma16(a, b, acc, 0);                                                      \
    __builtin_amdgcn_s_setprio(0);                                             \
    __builtin_amdgcn_s_barrier();                                              \
    /* P1: reads of the second M-half, B-stage, counted vmcnt for the NEXT  */ \
    /* tile's slot, barrier, lgkm0, MFMA.                                   */ \
    _Pragma("unroll")                                                          \
    for (int i = 0; i < 4; ++i)                                                \
      a[i] = *(const short8*)&slot[(wr * 128 + 64 + i * 16 + l15) * 32 + pcs]; \
    if (DO_STAGE) { STAGE_B(nslot, ((kt) + 3) * 32) }                          \
    asm volatile(WAITSTR ::: "memory");                                        \
    __builtin_amdgcn_s_barrier();                                              \
    asm volatile("s_waitcnt lgkmcnt(0)" ::: "memory");                         \
    __builtin_amdgcn_sched_barrier(0);                                         \
    __builtin_amdgcn_s_setprio(1);                                             \
    mfma16(a, b, acc, 4);                                                      \
    __builtin_amdgcn_s_setprio(0);                                             \
    __builtin_amdgcn_s_barrier();                                              \
  }

__global__ __launch_bounds__(512, 2) void mfma_gemm(const __hip_bfloat16* __restrict__ Ab,
                                                    const __hip_bfloat16* __restrict__ Wt,
                                                    __hip_bfloat16* __restrict__ XY,
                                                    float* __restrict__ ST,
                                                    float* __restrict__ CC) {
    __shared__ short lds[4 * SLOT_SH];   // 128 KiB
    int tid = threadIdx.x;
    int wave = tid >> 6, lane = tid & 63;
    int wr = wave >> 2, wc = wave & 3;
    int l15 = lane & 15;
    int pcs = ((lane >> 4) ^ ((l15 >> 1) & 3)) * 8;   // swizzled chunk, in shorts

    // bijective XCD swizzle: nwg=732, q=91, r=4 (m204 formula)
    int orig = blockIdx.x;
    int xcd = orig & 7, loc = orig >> 3;
    int wg = (xcd < 4 ? xcd * 92 : 368 + (xcd - 4) * 91) + loc;
    int mt = wg / 12, nt = wg - mt * 12;
    int m0 = mt << 8, n0 = nt << 8;

    const __hip_bfloat16* Bt;
    if (m0 < YB2)        Bt = Wt + (size_t)1 * HS_ * H_;  // X: h_end panel
    else if (m0 < GB)    Bt = Wt + (size_t)2 * HS_ * H_;  // Y: h_mean panel
    else if (m0 < CLSB)  Bt = Wt;                         // ST: h_start panel
    else                 Bt = Wt + (size_t)3 * HS_ * H_;  // CC: cls panel

    // staging addresses: wave w covers rows [w*16, w*16+16) and +128;
    // per-lane logical chunk lc = (lane&3) ^ ((row>>1)&3) = (lane&3)^((lane>>3)&3)
    int srow = wave * 16 + (lane >> 2);
    int lcS = ((lane & 3) ^ ((lane >> 3) & 3)) * 8;       // elements
    const __hip_bfloat16* pA = Ab + (size_t)(m0 + srow) * H_ + lcS;
    const __hip_bfloat16* pB = Bt + (size_t)(n0 + srow) * H_ + lcS;
    int dstoff = wave * 1024;                             // bytes within slot half

    f32x4 acc[8][4] = {};

    // prologue: stage tiles 0,1,2; then guard slot 0 (vmcnt(8): oldest 4 done)
#pragma unroll
    for (int t = 0; t < 3; ++t) {
        STAGE_A(lds + t * SLOT_SH, t * 32)
        STAGE_B(lds + t * SLOT_SH, t * 32)
    }
    asm volatile("s_waitcnt vmcnt(8)" ::: "memory");
    __builtin_amdgcn_s_barrier();

    for (int kt = 0; kt < NKT - 3; ++kt)
        TILE_STEP(kt, "s_waitcnt vmcnt(8)", true)
    TILE_STEP(NKT - 3, "s_waitcnt vmcnt(4)", false)
    TILE_STEP(NKT - 2, "s_waitcnt vmcnt(0)", false)
    TILE_STEP(NKT - 1, "s_waitcnt vmcnt(0)", false)

    // C-write. 16x16x32 C/D layout: col(n)=lane&15, row(m)=(lane>>4)*4+reg
    int mb = m0 + wr * 128, nb = n0 + wc * 64;
#pragma unroll
    for (int mf = 0; mf < 8; ++mf) {
#pragma unroll
        for (int nf = 0; nf < 4; ++nf) {
            int n = nb + nf * 16 + l15;
            int mr = mb + mf * 16 + (lane >> 4) * 4;
#pragma unroll
            for (int r = 0; r < 4; ++r) {
                int m = mr + r;
                float v = acc[mf][nf][r];
                if (m < XYROWS) {
                    XY[(size_t)m * HS_ + n] = __float2bfloat16(v);
                } else if (m < CLSB) {
                    ST[(size_t)(m - GB) * HS_ + n] = v;
                } else if (m < CLSB + 16) {
                    CC[(size_t)(m - CLSB) * HS_ + n] = v;
                }
            }
        }
    }
}

// ---------------------------------------------------------------------------
// c0 = bf16(ST + CC[b] + b1); tail blocks convert w_score -> bf16
// ---------------------------------------------------------------------------
__global__ __launch_bounds__(256) void c0_kernel(const float4* __restrict__ ST,
                                                 const float4* __restrict__ CC,
                                                 const float4* __restrict__ b1,
                                                 const float4* __restrict__ w_score,
                                                 ushort4* __restrict__ c0b,
                                                 ushort4* __restrict__ wb16) {
    if (blockIdx.x >= 512 * HS_ / 4 / 256) {
        int i = (blockIdx.x - 512 * HS_ / 4 / 256) * 256 + threadIdx.x;  // 0..767
        wb16[i] = pack4(w_score[i]);
        return;
    }
    int i = blockIdx.x * 256 + threadIdx.x;  // over 512*768 float4s
    int row = i / (HS_ / 4);
    int b = row >> 5;
    int c4 = i % (HS_ / 4);
    float4 s = ST[i], c = CC[b * (HS_ / 4) + c4], bb = b1[c4];
    float4 v = {s.x + c.x + bb.x, s.y + c.y + bb.y, s.z + c.z + bb.z, s.w + c.w + bb.w};
    c0b[i] = pack4(v);
}

// ---------------------------------------------------------------------------
// combine: one wave per (b,s, l-pair); l0=2p, l1=2p+1 share Ys/c0/w streams.
// grid x swizzled so XCD = x%8 = b%8 (batch's span rows share an XCD L2).
// ---------------------------------------------------------------------------
__global__ __launch_bounds__(256) void combine_kernel(
    const unsigned short* __restrict__ c0, const unsigned short* __restrict__ wb16,
    const __hip_bfloat16* __restrict__ XY,
    const float* __restrict__ b_score, const float* __restrict__ W_type,
    const int* __restrict__ starts, const int* __restrict__ ends,
    float* __restrict__ scores, float* __restrict__ tgold) {
    int x = blockIdx.x;
    int b = x & 15, s = x >> 4;          // XCD = x%8 = b%8
    int bs = b * S_ + s;
    int wave = threadIdx.x >> 6, lane = threadIdx.x & 63;
    int pr = blockIdx.y * 4 + wave;        // pair index 0..24
    if (pr >= L_ / 2) return;
    int l0 = pr * 2, l1 = l0 + 1;
    int sv = starts[bs], ev = ends[bs];
    int gi = min(max(ev - sv, 0), L_ - 1);
    int sc = min(max(sv, 0), TX_ - 1);
    int pc0 = min(max(sv + l0, 0), TX_ - 2);   // spec: <=448; clamp keeps in-bounds
    int pc1 = min(max(sv + l1, 0), TX_ - 2);
    float inv0 = 1.0f / (float)(l0 + 1);
    float inv1 = 1.0f / (float)(l1 + 1);
    bool isg0 = (l0 == gi), isg1 = (l1 == gi);
    bool anyg = isg0 || isg1;

    const unsigned short* X0 = (const unsigned short*)(XY + (size_t)(b * TX_ + pc0) * HS_);
    const unsigned short* X1 = (const unsigned short*)(XY + (size_t)(b * TX_ + pc1) * HS_);
    const unsigned short* Y0 = (const unsigned short*)(XY + (size_t)(YB2 + b * TX_ + pc0 + 1) * HS_);
    const unsigned short* Y1 = (const unsigned short*)(XY + (size_t)(YB2 + b * TX_ + pc1 + 1) * HS_);
    const unsigned short* Ysr = (const unsigned short*)(XY + (size_t)(YB2 + b * TX_ + sc) * HS_);
    const unsigned short* c0r = c0 + (size_t)bs * HS_;

    float local0 = 0.f, local1 = 0.f, t0 = 0.f, t1 = 0.f, t2 = 0.f;
#pragma unroll
    for (int j = 0; j < 6; j++) {
        int d = j * 512 + lane * 8;
        short8 xv0 = *(const short8*)(X0 + d);
        short8 xv1 = *(const short8*)(X1 + d);
        short8 yv0 = *(const short8*)(Y0 + d);
        short8 yv1 = *(const short8*)(Y1 + d);
        short8 sv8 = *(const short8*)(Ysr + d);
        short8 cv8 = *(const short8*)(c0r + d);
        short8 wv8 = *(const short8*)(wb16 + d);
#pragma unroll
        for (int q = 0; q < 8; q++) {
            float ys = bf2f(((const unsigned short*)&sv8)[q]);
            float cv = bf2f(((const unsigned short*)&cv8)[q]);
            float w  = bf2f(((const unsigned short*)&wv8)[q]);
            float v0 = fmaf(bf2f(((const unsigned short*)&yv0)[q]) - ys, inv0, cv) +
                       bf2f(((const unsigned short*)&xv0)[q]);
            float v1 = fmaf(bf2f(((const unsigned short*)&yv1)[q]) - ys, inv1, cv) +
                       bf2f(((const unsigned short*)&xv1)[q]);
            float g0 = gelu_exact(v0);
            float g1 = gelu_exact(v1);
            local0 = fmaf(g0, w, local0);
            local1 = fmaf(g1, w, local1);
            if (anyg) {   // wave-uniform branch
                float gg = isg0 ? g0 : g1;
                t0 = fmaf(gg, W_type[(d + q) * NT_ + 0], t0);
                t1 = fmaf(gg, W_type[(d + q) * NT_ + 1], t1);
                t2 = fmaf(gg, W_type[(d + q) * NT_ + 2], t2);
            }
        }
    }
#pragma unroll
    for (int off = 32; off >= 1; off >>= 1) {
        local0 += __shfl_down(local0, off);
        local1 += __shfl_down(local1, off);
    }
    if (lane == 0) {
        float bs0 = b_score[0];
        scores[(size_t)bs * L_ + l0] = local0 + bs0;
        scores[(size_t)bs * L_ + l1] = local1 + bs0;
    }
    if (anyg) {
#pragma unroll
        for (int off = 32; off >= 1; off >>= 1) {
            t0 += __shfl_down(t0, off);
            t1 += __shfl_down(t1, off);
            t2 += __shfl_down(t2, off);
        }
        if (lane == 0) {
            tgold[bs * NT_ + 0] = t0;
            tgold[bs * NT_ + 1] = t1;
            tgold[bs * NT_ + 2] = t2;
        }
    }
}

// ---------------------------------------------------------------------------
// final loss: one block, one thread per (b,s)
// ---------------------------------------------------------------------------
__global__ __launch_bounds__(512) void loss_kernel(
    const float* __restrict__ scores, const float* __restrict__ tgold,
    const int* __restrict__ mask, const int* __restrict__ starts,
    const int* __restrict__ ends, const int* __restrict__ types,
    const float* __restrict__ b_type, float* __restrict__ out) {
    __shared__ int svl[B_];
    __shared__ float r[3][8];
    int tid = threadIdx.x;
    int b = tid / S_;
    if (tid < B_) svl[tid] = 0;
    __syncthreads();
    {
        int part = 0;
        const int* mp = mask + tid * 16;
#pragma unroll
        for (int i = 0; i < 16; i++) part += mp[i];
        atomicAdd(&svl[tid / (T_ / 16)], part);
    }
    __syncthreads();
    int vl = svl[b];
    int lt = max(1, vl - 2);
    int sv = starts[tid], ev = ends[tid];
    int gold = ev - sv;
    bool valid = (sv >= 1) && (sv <= lt) && (ev >= sv) && (ev <= lt) && (gold < L_);
    int emax = min(sv + L_ - 1, lt);
    const float* sp = scores + (size_t)tid * L_;
    float m = -1e30f;
    for (int l = 0; l < L_; l++) {
        float v = (sv + l <= emax) ? sp[l] : -1e9f;
        m = fmaxf(m, v);
    }
    float sum = 0.f;
    for (int l = 0; l < L_; l++) {
        float v = (sv + l <= emax) ? sp[l] : -1e9f;
        sum += expf(v - m);
    }
    int gi = min(max(gold, 0), L_ - 1);
    float vg = (sv + gi <= emax) ? sp[gi] : -1e9f;
    float end_loss = (m + logf(sum)) - vg;

    float t0 = tgold[tid * 3 + 0] + b_type[0];
    float t1 = tgold[tid * 3 + 1] + b_type[1];
    float t2 = tgold[tid * 3 + 2] + b_type[2];
    float tm = fmaxf(t0, fmaxf(t1, t2));
    float tsum = expf(t0 - tm) + expf(t1 - tm) + expf(t2 - tm);
    int tg = min(max(types[tid], 0), NT_ - 1);
    float tv = (tg == 0) ? t0 : ((tg == 1) ? t1 : t2);
    float type_loss = (tm + logf(tsum)) - tv;

    float ve = valid ? end_loss : 0.f;
    float vt = valid ? type_loss : 0.f;
    float vc = valid ? 1.f : 0.f;
    for (int off = 32; off >= 1; off >>= 1) {
        ve += __shfl_down(ve, off);
        vt += __shfl_down(vt, off);
        vc += __shfl_down(vc, off);
    }
    if ((tid & 63) == 0) {
        int w = tid >> 6;
        r[0][w] = ve; r[1][w] = vt; r[2][w] = vc;
    }
    __syncthreads();
    if (tid == 0) {
        float se = 0, st = 0, n = 0;
        for (int w = 0; w < 8; w++) { se += r[0][w]; st += r[1][w]; n += r[2][w]; }
        float denom = fmaxf(n, 1.f);
        out[0] = (n > 0.f) ? (se / denom + st / denom) : 0.f;
    }
}

// ---------------------------------------------------------------------------
extern "C" void kernel_launch(void* const* d_in, const int* in_sizes, int n_in,
                              void* d_out, int out_size, void* d_ws, size_t ws_size,
                              hipStream_t stream) {
    const float* h       = (const float*)d_in[0];
    const int*   mask    = (const int*)d_in[1];
    const int*   starts  = (const int*)d_in[2];
    const int*   ends    = (const int*)d_in[3];
    const int*   types   = (const int*)d_in[4];
    const float* W1      = (const float*)d_in[5];
    const float* b1      = (const float*)d_in[6];
    const float* w_score = (const float*)d_in[7];
    const float* b_score = (const float*)d_in[8];
    const float* W_type  = (const float*)d_in[9];
    const float* b_type  = (const float*)d_in[10];
    float* out = (float*)d_out;

    char* ws = (char*)d_ws;
    size_t off = 0;
    __hip_bfloat16* Ab = (__hip_bfloat16*)(ws + off); off += (size_t)AROWS * H_ * 2;
    __hip_bfloat16* XY = (__hip_bfloat16*)(ws + off); off += (size_t)XYROWS * HS_ * 2;
    __hip_bfloat16* Wt = (__hip_bfloat16*)(ws + off); off += (size_t)4 * HS_ * H_ * 2;
    float* ST     = (float*)(ws + off);               off += (size_t)512 * HS_ * 4;
    float* CC     = (float*)(ws + off);               off += (size_t)16 * HS_ * 4;
    unsigned short* c0b = (unsigned short*)(ws + off); off += (size_t)512 * HS_ * 2;
    unsigned short* wb16 = (unsigned short*)(ws + off); off += (size_t)HS_ * 2;
    float* scores = (float*)(ws + off);               off += (size_t)B_ * S_ * L_ * 4;
    float* tgold  = (float*)(ws + off);               off += (size_t)B_ * S_ * NT_ * 4;
    float4* partial = (float4*)XY;  // aliases XY; consumed by pass3 before GEMM writes XY

    hipLaunchKernelGGL(cumsum_pass1, dim3(B_ * CH_ * 192 / 256), dim3(256), 0, stream,
                       (const float4*)h, partial);
    hipLaunchKernelGGL(cumsum_pass3, dim3(B_ * CH_ * 192 / 256), dim3(256), 0, stream,
                       (const float4*)h, (const float4*)partial, (ushort4*)Ab);
    hipLaunchKernelGGL(gather_kernel, dim3(B_ * S_ + B_), dim3(256), 0, stream, h, starts, Ab);
    hipLaunchKernelGGL(transpose_w, dim3(48, 48), dim3(256), 0, stream, W1, Wt);
    hipLaunchKernelGGL(mfma_gemm, dim3((AROWS / 256) * 12), dim3(512), 0, stream,
                       Ab, Wt, XY, ST, CC);
    hipLaunchKernelGGL(c0_kernel, dim3(512 * HS_ / 4 / 256 + 3), dim3(256), 0, stream,
                       (const float4*)ST, (const float4*)CC, (const float4*)b1,
                       (const float4*)w_score, (ushort4*)c0b, (ushort4*)wb16);
    hipLaunchKernelGGL(combine_kernel, dim3(B_ * S_, 7), dim3(256), 0, stream,
                       c0b, wb16, XY, b_score, W_type, starts, ends, scores, tgold);
    hipLaunchKernelGGL(loss_kernel, dim3(1), dim3(512), 0, stream,
                       scores, tgold, mask, starts, ends, types, b_type, out);
}

// Round 4
// 316.024 us; speedup vs baseline: 1.0064x; 1.0064x over previous
//
#include <hip/hip_runtime.h>
#include <hip/hip_bf16.h>
#include <math.h>

#define B_ 16
#define T_ 512
#define H_ 768
#define S_ 32
#define L_ 50
#define NT_ 3
#define HS_ 3072
#define CH_ 32
#define CT_ 16  // T_/CH_

// Row compaction: starts in [1,400), L=50  =>  pc <= 448, pre-index <= 449.
// TX_=464 rows/batch (29*16 chunks); regions 256-aligned (=> also 128-aligned,
// so every 128-row GEMM m-tile uses a single W-panel).
#define TX_ 464
// A-buffer row layout (bf16, 768 cols), compacted:
//   [0, 7424)        hb   = bf16(h[b,t]), row b*464+t, t<464
//   [7424, 14848)    preb = bf16(cumsum), row 7424 + b*464 + u
//   [14848, 15360)   Gb   = gathered span-start rows (512)
//   [15360, 15376)   cls rows (16); rows 15376..15615 pad (discarded)
#define YB2 7424
#define GB 14848
#define CLSB 15360
#define XYROWS 14848
#define AROWS 15616        // = 122 * 128 exactly
#define NKT 24             // 768 / BK32
#define GSLOT 8192         // shorts per LDS slot: A 4096 + B 4096 (16 KiB)

typedef __attribute__((ext_vector_type(8))) short short8;
typedef __attribute__((ext_vector_type(4))) float f32x4;

__device__ __forceinline__ unsigned short f2bf(float f) {
    __hip_bfloat16 b = __float2bfloat16(f);
    return *(unsigned short*)&b;
}
__device__ __forceinline__ float bf2f(unsigned short u) {
    union { unsigned int i; float f; } v; v.i = ((unsigned int)u) << 16; return v.f;
}
__device__ __forceinline__ void load_lds16(const void* g, void* l) {
    __builtin_amdgcn_global_load_lds((__attribute__((address_space(1))) void*)g,
                                     (__attribute__((address_space(3))) void*)l, 16, 0, 0);
}
__device__ __forceinline__ ushort4 pack4(float4 v) {
    ushort4 o; o.x = f2bf(v.x); o.y = f2bf(v.y); o.z = f2bf(v.z); o.w = f2bf(v.w);
    return o;
}

// branch-free exact-gelu: Abramowitz-Stegun 3-term erf, max err 2.5e-5
__device__ __forceinline__ float gelu_exact(float v) {
    float a = fabsf(v) * 0.70710678118654752f;
    float t = __builtin_amdgcn_rcpf(fmaf(a, 0.47047f, 1.0f));
    float poly = t * fmaf(t, fmaf(t, 0.7478556f, -0.0958798f), 0.3480242f);
    float e = __builtin_amdgcn_exp2f(a * a * -1.4426950408889634f);
    float erfa = fmaf(-poly, e, 1.0f);
    float erfv = copysignf(erfa, v);
    return 0.5f * v * (1.0f + erfv);
}

// ---------------------------------------------------------------------------
// cumsum pass1: per-(b,chunk) partial sums, float4-vectorized over hd
// ---------------------------------------------------------------------------
__global__ __launch_bounds__(256) void cumsum_pass1(const float4* __restrict__ h4,
                                                    float4* __restrict__ partial) {
    int idx = blockIdx.x * 256 + threadIdx.x;        // (b, ch, hd4)
    int hd4 = idx % 192; int t = idx / 192; int ch = t % CH_; int b = t / CH_;
    const float4* hp = h4 + ((size_t)b * T_ + ch * CT_) * 192 + hd4;
    float4 acc = {0.f, 0.f, 0.f, 0.f};
#pragma unroll
    for (int tt = 0; tt < CT_; tt++) {
        float4 v = hp[(size_t)tt * 192];
        acc.x += v.x; acc.y += v.y; acc.z += v.z; acc.w += v.w;
    }
    partial[idx] = acc;
}

// pass3 (chunk prefix folded in): emit bf16 h + bf16 cumsum into compacted A.
// Dead chunks early-out.
__global__ __launch_bounds__(256) void cumsum_pass3(const float4* __restrict__ h4,
                                                    const float4* __restrict__ partial,
                                                    ushort4* __restrict__ Ab4) {
    int idx = blockIdx.x * 256 + threadIdx.x;        // (b, ch, hd4)
    int hd4 = idx % 192; int t = idx / 192; int ch = t % CH_; int b = t / CH_;
    if (ch * CT_ >= TX_) return;                     // dead chunk
    float4 acc = {0.f, 0.f, 0.f, 0.f};
#pragma unroll
    for (int c = 0; c < CH_; c++) {
        if (c < ch) {
            float4 v = partial[((size_t)b * CH_ + c) * 192 + hd4];
            acc.x += v.x; acc.y += v.y; acc.z += v.z; acc.w += v.w;
        }
    }
    const float4* hp = h4 + ((size_t)b * T_ + ch * CT_) * 192 + hd4;
    if (ch == 0) {
        ushort4 z = {0, 0, 0, 0};
        Ab4[((size_t)(YB2 + b * TX_)) * 192 + hd4] = z;   // pre[b][0] = 0
    }
#pragma unroll
    for (int tt = 0; tt < CT_; tt++) {
        int t2 = ch * CT_ + tt;
        float4 hv = hp[(size_t)tt * 192];
        if (t2 < TX_)
            Ab4[((size_t)(b * TX_ + t2)) * 192 + hd4] = pack4(hv);
        acc.x += hv.x; acc.y += hv.y; acc.z += hv.z; acc.w += hv.w;
        if (t2 + 1 < TX_)
            Ab4[((size_t)(YB2 + b * TX_ + t2 + 1)) * 192 + hd4] = pack4(acc);
    }
}

// ---------------------------------------------------------------------------
// gather span-start rows (512) + cls rows (16) into A
// ---------------------------------------------------------------------------
__global__ void gather_kernel(const float* __restrict__ h,
                              const int* __restrict__ starts,
                              __hip_bfloat16* __restrict__ Ab) {
    int r = blockIdx.x;
    int src_row, dst_row;
    if (r < B_ * S_) {
        int b = r / S_;
        int sv = starts[r];
        int sc = min(max(sv, 0), T_ - 1);
        src_row = b * T_ + sc;
        dst_row = GB + r;
    } else {
        int b = r - B_ * S_;
        src_row = b * T_;
        dst_row = CLSB + b;
    }
    __hip_bfloat16* dst = Ab + (size_t)dst_row * H_;
    const float* src = h + (size_t)src_row * H_;
    for (int j = threadIdx.x; j < H_; j += 256)
        dst[j] = __float2bfloat16(src[j]);
}

// ---------------------------------------------------------------------------
// W1 (3072x3072 fp32) -> 4 transposed bf16 panels Wt[p][n=3072][k=768]
// ---------------------------------------------------------------------------
__global__ __launch_bounds__(256) void transpose_w(const float* __restrict__ W1,
                                                   __hip_bfloat16* __restrict__ Wt) {
    __shared__ float tile[64][65];
    int n0 = blockIdx.x * 64, k0 = blockIdx.y * 64;
    int c = threadIdx.x & 63, r0 = threadIdx.x >> 6;
#pragma unroll
    for (int i = 0; i < 16; i++) {
        int r = r0 + i * 4;
        tile[r][c] = W1[(size_t)(k0 + r) * HS_ + n0 + c];
    }
    __syncthreads();
    int p = k0 / H_, kl = k0 % H_;
    __hip_bfloat16* out = Wt + (size_t)p * HS_ * H_;
#pragma unroll
    for (int i = 0; i < 16; i++) {
        int r = r0 + i * 4;
        out[(size_t)(n0 + r) * H_ + kl + c] = __float2bfloat16(tile[c][r]);
    }
}

// ---------------------------------------------------------------------------
// mega MFMA GEMM over 15616 compacted A rows (X | Y | ST | CC+pad).
// m97-mechanism port: 128x128 tile, 4 waves (2x2), wave-tile 64x64,
// 16x16x32 bf16, BK=32, acc = 64 regs/wave -> ~150 total regs/wave
// -> 3 waves/SIMD -> 3 blocks/CU (LDS 32 KiB/block). Cross-block wave
// overlap hides barrier/load stalls implicitly (m97/m114 mechanism) —
// rounds 1-3 proved in-block pipelining at 1 block/CU stays at 27-30%.
// LDS: 2-slot ring, slot = one K-tile (A 8K | B 8K = 16 KiB).
// XOR swizzle (PMC-verified 0 conflicts in r2): 16B chunk p of row r holds
// logical chunk p ^ ((r>>1)&3); applied via per-lane pre-swizzled GLOBAL
// source (global_load_lds dest stays linear) + swizzled ds_read chunk.
// Counted vmcnt: stage kt+1 (4 loads/wave) while computing kt; vmcnt(4)
// waits only kt's loads; 2 barriers/tile; drain vmcnt(0) on last tile only.
// grid: 2928 = 8*366 blocks, exact XCD swizzle (n-fastest within XCD chunk).
// ---------------------------------------------------------------------------
__global__ __launch_bounds__(256, 3) void mfma_gemm(const __hip_bfloat16* __restrict__ Ab,
                                                    const __hip_bfloat16* __restrict__ Wt,
                                                    __hip_bfloat16* __restrict__ XY,
                                                    float* __restrict__ ST,
                                                    float* __restrict__ CC) {
    __shared__ short lds[2 * GSLOT];   // 32 KiB
    int tid = threadIdx.x;
    int wave = tid >> 6, lane = tid & 63;
    int wr = wave >> 1, wc = wave & 1;
    int l15 = lane & 15;
    int pcs = ((lane >> 4) ^ ((l15 >> 1) & 3)) * 8;   // swizzled chunk, shorts

    // exact XCD swizzle: 2928 = 8 * 366
    int orig = blockIdx.x;
    int wg = (orig & 7) * 366 + (orig >> 3);
    int mt = wg / 24, nt = wg - mt * 24;
    int m0 = mt << 7, n0 = nt << 7;

    const __hip_bfloat16* Bt;
    if (m0 < YB2)        Bt = Wt + (size_t)1 * HS_ * H_;  // X: h_end panel
    else if (m0 < GB)    Bt = Wt + (size_t)2 * HS_ * H_;  // Y: h_mean panel
    else if (m0 < CLSB)  Bt = Wt;                         // ST: h_start panel
    else                 Bt = Wt + (size_t)3 * HS_ * H_;  // CC: cls panel

    // staging: per wave 2 A-loads + 2 B-loads. Load j covers LDS bytes
    // [(wave*2+j)*1024, +1024) of the A (or B) half; lane's chunk
    // cid = (wave*2+j)*64 + lane -> row = cid>>2, pc = cid&3,
    // logical chunk lc = pc ^ ((row>>1)&3)  (pre-swizzled global source).
    int cid0 = wave * 128 + lane;          // j=0
    int cid1 = cid0 + 64;                  // j=1
    int row0 = cid0 >> 2, row1 = cid1 >> 2;
    int lc0 = ((cid0 & 3) ^ ((row0 >> 1) & 3)) * 8;   // elements
    int lc1 = ((cid1 & 3) ^ ((row1 >> 1) & 3)) * 8;
    const __hip_bfloat16* pA0 = Ab + (size_t)(m0 + row0) * H_ + lc0;
    const __hip_bfloat16* pA1 = Ab + (size_t)(m0 + row1) * H_ + lc1;
    const __hip_bfloat16* pB0 = Bt + (size_t)(n0 + row0) * H_ + lc0;
    const __hip_bfloat16* pB1 = Bt + (size_t)(n0 + row1) * H_ + lc1;
    int dstoff = wave * 2048;              // bytes within slot half

#define STAGE2(kt_) {                                                          \
    char* da = (char*)lds + ((kt_) & 1) * (GSLOT * 2) + dstoff;                \
    load_lds16(pA0 + (kt_) * 32, da);                                          \
    load_lds16(pA1 + (kt_) * 32, da + 1024);                                   \
    load_lds16(pB0 + (kt_) * 32, da + 8192);                                   \
    load_lds16(pB1 + (kt_) * 32, da + 9216);                                   \
}

    f32x4 acc[4][4] = {};

    // prologue: stage tile 0 into slot 0
    STAGE2(0)

    for (int kt = 0; kt < NKT; ++kt) {
        const short* cur = lds + (kt & 1) * GSLOT;
        if (kt + 1 < NKT) {
            STAGE2(kt + 1)
            asm volatile("s_waitcnt vmcnt(4)" ::: "memory");   // kt's 4 done
        } else {
            asm volatile("s_waitcnt vmcnt(0)" ::: "memory");
        }
        __builtin_amdgcn_s_barrier();          // kt's tile visible to all
        __builtin_amdgcn_sched_barrier(0);
        short8 a[4], b[4];
#pragma unroll
        for (int f = 0; f < 4; ++f)
            a[f] = *(const short8*)&cur[(wr * 64 + f * 16 + l15) * 32 + pcs];
#pragma unroll
        for (int f = 0; f < 4; ++f)
            b[f] = *(const short8*)&cur[4096 + (wc * 64 + f * 16 + l15) * 32 + pcs];
#pragma unroll
        for (int fm = 0; fm < 4; ++fm)
#pragma unroll
            for (int fn = 0; fn < 4; ++fn)
                acc[fm][fn] = __builtin_amdgcn_mfma_f32_16x16x32_bf16(
                    a[fm], b[fn], acc[fm][fn], 0, 0, 0);
        __builtin_amdgcn_sched_barrier(0);     // pin reads before barrier #2
        __builtin_amdgcn_s_barrier();          // all reads of cur done
    }

    // C-write. 16x16x32 C/D layout: col(n)=lane&15, row(m)=(lane>>4)*4+reg
    int mb = m0 + wr * 64, nb = n0 + wc * 64;
#pragma unroll
    for (int fm = 0; fm < 4; ++fm) {
#pragma unroll
        for (int fn = 0; fn < 4; ++fn) {
            int n = nb + fn * 16 + l15;
            int mr = mb + fm * 16 + (lane >> 4) * 4;
#pragma unroll
            for (int r = 0; r < 4; ++r) {
                int m = mr + r;
                float v = acc[fm][fn][r];
                if (m < XYROWS) {
                    XY[(size_t)m * HS_ + n] = __float2bfloat16(v);
                } else if (m < CLSB) {
                    ST[(size_t)(m - GB) * HS_ + n] = v;
                } else if (m < CLSB + 16) {
                    CC[(size_t)(m - CLSB) * HS_ + n] = v;
                }
            }
        }
    }
#undef STAGE2
}

// ---------------------------------------------------------------------------
// c0 = bf16(ST + CC[b] + b1); tail blocks convert w_score -> bf16
// ---------------------------------------------------------------------------
__global__ __launch_bounds__(256) void c0_kernel(const float4* __restrict__ ST,
                                                 const float4* __restrict__ CC,
                                                 const float4* __restrict__ b1,
                                                 const float4* __restrict__ w_score,
                                                 ushort4* __restrict__ c0b,
                                                 ushort4* __restrict__ wb16) {
    if (blockIdx.x >= 512 * HS_ / 4 / 256) {
        int i = (blockIdx.x - 512 * HS_ / 4 / 256) * 256 + threadIdx.x;  // 0..767
        wb16[i] = pack4(w_score[i]);
        return;
    }
    int i = blockIdx.x * 256 + threadIdx.x;  // over 512*768 float4s
    int row = i / (HS_ / 4);
    int b = row >> 5;
    int c4 = i % (HS_ / 4);
    float4 s = ST[i], c = CC[b * (HS_ / 4) + c4], bb = b1[c4];
    float4 v = {s.x + c.x + bb.x, s.y + c.y + bb.y, s.z + c.z + bb.z, s.w + c.w + bb.w};
    c0b[i] = pack4(v);
}

// ---------------------------------------------------------------------------
// combine: one wave per (b,s, l-pair); l0=2p, l1=2p+1 share Ys/c0/w streams.
// grid x swizzled so XCD = x%8 = b%8 (batch's span rows share an XCD L2).
// ---------------------------------------------------------------------------
__global__ __launch_bounds__(256) void combine_kernel(
    const unsigned short* __restrict__ c0, const unsigned short* __restrict__ wb16,
    const __hip_bfloat16* __restrict__ XY,
    const float* __restrict__ b_score, const float* __restrict__ W_type,
    const int* __restrict__ starts, const int* __restrict__ ends,
    float* __restrict__ scores, float* __restrict__ tgold) {
    int x = blockIdx.x;
    int b = x & 15, s = x >> 4;          // XCD = x%8 = b%8
    int bs = b * S_ + s;
    int wave = threadIdx.x >> 6, lane = threadIdx.x & 63;
    int pr = blockIdx.y * 4 + wave;        // pair index 0..24
    if (pr >= L_ / 2) return;
    int l0 = pr * 2, l1 = l0 + 1;
    int sv = starts[bs], ev = ends[bs];
    int gi = min(max(ev - sv, 0), L_ - 1);
    int sc = min(max(sv, 0), TX_ - 1);
    int pc0 = min(max(sv + l0, 0), TX_ - 2);   // spec: <=448; clamp keeps in-bounds
    int pc1 = min(max(sv + l1, 0), TX_ - 2);
    float inv0 = 1.0f / (float)(l0 + 1);
    float inv1 = 1.0f / (float)(l1 + 1);
    bool isg0 = (l0 == gi), isg1 = (l1 == gi);
    bool anyg = isg0 || isg1;

    const unsigned short* X0 = (const unsigned short*)(XY + (size_t)(b * TX_ + pc0) * HS_);
    const unsigned short* X1 = (const unsigned short*)(XY + (size_t)(b * TX_ + pc1) * HS_);
    const unsigned short* Y0 = (const unsigned short*)(XY + (size_t)(YB2 + b * TX_ + pc0 + 1) * HS_);
    const unsigned short* Y1 = (const unsigned short*)(XY + (size_t)(YB2 + b * TX_ + pc1 + 1) * HS_);
    const unsigned short* Ysr = (const unsigned short*)(XY + (size_t)(YB2 + b * TX_ + sc) * HS_);
    const unsigned short* c0r = c0 + (size_t)bs * HS_;

    float local0 = 0.f, local1 = 0.f, t0 = 0.f, t1 = 0.f, t2 = 0.f;
#pragma unroll
    for (int j = 0; j < 6; j++) {
        int d = j * 512 + lane * 8;
        short8 xv0 = *(const short8*)(X0 + d);
        short8 xv1 = *(const short8*)(X1 + d);
        short8 yv0 = *(const short8*)(Y0 + d);
        short8 yv1 = *(const short8*)(Y1 + d);
        short8 sv8 = *(const short8*)(Ysr + d);
        short8 cv8 = *(const short8*)(c0r + d);
        short8 wv8 = *(const short8*)(wb16 + d);
#pragma unroll
        for (int q = 0; q < 8; q++) {
            float ys = bf2f(((const unsigned short*)&sv8)[q]);
            float cv = bf2f(((const unsigned short*)&cv8)[q]);
            float w  = bf2f(((const unsigned short*)&wv8)[q]);
            float v0 = fmaf(bf2f(((const unsigned short*)&yv0)[q]) - ys, inv0, cv) +
                       bf2f(((const unsigned short*)&xv0)[q]);
            float v1 = fmaf(bf2f(((const unsigned short*)&yv1)[q]) - ys, inv1, cv) +
                       bf2f(((const unsigned short*)&xv1)[q]);
            float g0 = gelu_exact(v0);
            float g1 = gelu_exact(v1);
            local0 = fmaf(g0, w, local0);
            local1 = fmaf(g1, w, local1);
            if (anyg) {   // wave-uniform branch
                float gg = isg0 ? g0 : g1;
                t0 = fmaf(gg, W_type[(d + q) * NT_ + 0], t0);
                t1 = fmaf(gg, W_type[(d + q) * NT_ + 1], t1);
                t2 = fmaf(gg, W_type[(d + q) * NT_ + 2], t2);
            }
        }
    }
#pragma unroll
    for (int off = 32; off >= 1; off >>= 1) {
        local0 += __shfl_down(local0, off);
        local1 += __shfl_down(local1, off);
    }
    if (lane == 0) {
        float bs0 = b_score[0];
        scores[(size_t)bs * L_ + l0] = local0 + bs0;
        scores[(size_t)bs * L_ + l1] = local1 + bs0;
    }
    if (anyg) {
#pragma unroll
        for (int off = 32; off >= 1; off >>= 1) {
            t0 += __shfl_down(t0, off);
            t1 += __shfl_down(t1, off);
            t2 += __shfl_down(t2, off);
        }
        if (lane == 0) {
            tgold[bs * NT_ + 0] = t0;
            tgold[bs * NT_ + 1] = t1;
            tgold[bs * NT_ + 2] = t2;
        }
    }
}

// ---------------------------------------------------------------------------
// final loss: one block, one thread per (b,s)
// ---------------------------------------------------------------------------
__global__ __launch_bounds__(512) void loss_kernel(
    const float* __restrict__ scores, const float* __restrict__ tgold,
    const int* __restrict__ mask, const int* __restrict__ starts,
    const int* __restrict__ ends, const int* __restrict__ types,
    const float* __restrict__ b_type, float* __restrict__ out) {
    __shared__ int svl[B_];
    __shared__ float r[3][8];
    int tid = threadIdx.x;
    int b = tid / S_;
    if (tid < B_) svl[tid] = 0;
    __syncthreads();
    {
        int part = 0;
        const int* mp = mask + tid * 16;
#pragma unroll
        for (int i = 0; i < 16; i++) part += mp[i];
        atomicAdd(&svl[tid / (T_ / 16)], part);
    }
    __syncthreads();
    int vl = svl[b];
    int lt = max(1, vl - 2);
    int sv = starts[tid], ev = ends[tid];
    int gold = ev - sv;
    bool valid = (sv >= 1) && (sv <= lt) && (ev >= sv) && (ev <= lt) && (gold < L_);
    int emax = min(sv + L_ - 1, lt);
    const float* sp = scores + (size_t)tid * L_;
    float m = -1e30f;
    for (int l = 0; l < L_; l++) {
        float v = (sv + l <= emax) ? sp[l] : -1e9f;
        m = fmaxf(m, v);
    }
    float sum = 0.f;
    for (int l = 0; l < L_; l++) {
        float v = (sv + l <= emax) ? sp[l] : -1e9f;
        sum += expf(v - m);
    }
    int gi = min(max(gold, 0), L_ - 1);
    float vg = (sv + gi <= emax) ? sp[gi] : -1e9f;
    float end_loss = (m + logf(sum)) - vg;

    float t0 = tgold[tid * 3 + 0] + b_type[0];
    float t1 = tgold[tid * 3 + 1] + b_type[1];
    float t2 = tgold[tid * 3 + 2] + b_type[2];
    float tm = fmaxf(t0, fmaxf(t1, t2));
    float tsum = expf(t0 - tm) + expf(t1 - tm) + expf(t2 - tm);
    int tg = min(max(types[tid], 0), NT_ - 1);
    float tv = (tg == 0) ? t0 : ((tg == 1) ? t1 : t2);
    float type_loss = (tm + logf(tsum)) - tv;

    float ve = valid ? end_loss : 0.f;
    float vt = valid ? type_loss : 0.f;
    float vc = valid ? 1.f : 0.f;
    for (int off = 32; off >= 1; off >>= 1) {
        ve += __shfl_down(ve, off);
        vt += __shfl_down(vt, off);
        vc += __shfl_down(vc, off);
    }
    if ((tid & 63) == 0) {
        int w = tid >> 6;
        r[0][w] = ve; r[1][w] = vt; r[2][w] = vc;
    }
    __syncthreads();
    if (tid == 0) {
        float se = 0, st = 0, n = 0;
        for (int w = 0; w < 8; w++) { se += r[0][w]; st += r[1][w]; n += r[2][w]; }
        float denom = fmaxf(n, 1.f);
        out[0] = (n > 0.f) ? (se / denom + st / denom) : 0.f;
    }
}

// ---------------------------------------------------------------------------
extern "C" void kernel_launch(void* const* d_in, const int* in_sizes, int n_in,
                              void* d_out, int out_size, void* d_ws, size_t ws_size,
                              hipStream_t stream) {
    const float* h       = (const float*)d_in[0];
    const int*   mask    = (const int*)d_in[1];
    const int*   starts  = (const int*)d_in[2];
    const int*   ends    = (const int*)d_in[3];
    const int*   types   = (const int*)d_in[4];
    const float* W1      = (const float*)d_in[5];
    const float* b1      = (const float*)d_in[6];
    const float* w_score = (const float*)d_in[7];
    const float* b_score = (const float*)d_in[8];
    const float* W_type  = (const float*)d_in[9];
    const float* b_type  = (const float*)d_in[10];
    float* out = (float*)d_out;

    char* ws = (char*)d_ws;
    size_t off = 0;
    __hip_bfloat16* Ab = (__hip_bfloat16*)(ws + off); off += (size_t)AROWS * H_ * 2;
    __hip_bfloat16* XY = (__hip_bfloat16*)(ws + off); off += (size_t)XYROWS * HS_ * 2;
    __hip_bfloat16* Wt = (__hip_bfloat16*)(ws + off); off += (size_t)4 * HS_ * H_ * 2;
    float* ST     = (float*)(ws + off);               off += (size_t)512 * HS_ * 4;
    float* CC     = (float*)(ws + off);               off += (size_t)16 * HS_ * 4;
    unsigned short* c0b = (unsigned short*)(ws + off); off += (size_t)512 * HS_ * 2;
    unsigned short* wb16 = (unsigned short*)(ws + off); off += (size_t)HS_ * 2;
    float* scores = (float*)(ws + off);               off += (size_t)B_ * S_ * L_ * 4;
    float* tgold  = (float*)(ws + off);               off += (size_t)B_ * S_ * NT_ * 4;
    float4* partial = (float4*)XY;  // aliases XY; consumed by pass3 before GEMM writes XY

    hipLaunchKernelGGL(cumsum_pass1, dim3(B_ * CH_ * 192 / 256), dim3(256), 0, stream,
                       (const float4*)h, partial);
    hipLaunchKernelGGL(cumsum_pass3, dim3(B_ * CH_ * 192 / 256), dim3(256), 0, stream,
                       (const float4*)h, (const float4*)partial, (ushort4*)Ab);
    hipLaunchKernelGGL(gather_kernel, dim3(B_ * S_ + B_), dim3(256), 0, stream, h, starts, Ab);
    hipLaunchKernelGGL(transpose_w, dim3(48, 48), dim3(256), 0, stream, W1, Wt);
    hipLaunchKernelGGL(mfma_gemm, dim3((AROWS / 128) * (HS_ / 128)), dim3(256), 0, stream,
                       Ab, Wt, XY, ST, CC);
    hipLaunchKernelGGL(c0_kernel, dim3(512 * HS_ / 4 / 256 + 3), dim3(256), 0, stream,
                       (const float4*)ST, (const float4*)CC, (const float4*)b1,
                       (const float4*)w_score, (ushort4*)c0b, (ushort4*)wb16);
    hipLaunchKernelGGL(combine_kernel, dim3(B_ * S_, 7), dim3(256), 0, stream,
                       c0b, wb16, XY, b_score, W_type, starts, ends, scores, tgold);
    hipLaunchKernelGGL(loss_kernel, dim3(1), dim3(512), 0, stream,
                       scores, tgold, mask, starts, ends, types, b_type, out);
}